// Round 8
// baseline (145.974 us; speedup 1.0000x reference)
//
#include <hip/hip_runtime.h>
#include <cstdint>

// Lukasiewicz max-plus matmul: y[n,o] = max(b[o], max(0, max_i(x[n,i]+a[o,i]-1)))
// N=2048, K=512, OUT=512, fp32.
//
// R8: 4 cols/lane. R7 cycle model: per-CU VALU 16.4k cyc vs LDS-return 16.4k
// cyc (broadcast ds_read_b128 still moves 1024B to the RF -> ~4cyc) = two
// co-critical pipes. 4 cols/lane halves DS to 8.2k -> VALU-bound again.
// Block = 1024 thr (16 waves) x 16 rows x 256 cols, 16-way k-split (wave w
// owns k4 in [8w,8w+8)), grid (2,128) = 256 blocks = exactly 1 block/CU
// (no tail), 4 waves/SIMD. A dbl-buffered in regs from transposed Apb;
// X slab 32KB LDS broadcast; 16-way merge via 64KB red buffer (96KB total).

#define NROW 2048
#define NK   512
#define NCOL 512
#define RPB  16                   // rows per block
#define CBL  256                  // cols per block (4 per lane)
#define KQ   8                    // k4-steps per wave (128 / 16 waves)
typedef float f32x4 __attribute__((ext_vector_type(4)));

__device__ __forceinline__ void async_load16(const float* g, float* l) {
  __builtin_amdgcn_global_load_lds(
      (const __attribute__((address_space(1))) void*)g,
      (__attribute__((address_space(3))) void*)l, 16, 0, 0);
}

// ---- prep: Apb[((o>>8)*128 + k4)*256 + (o&255)] = A[o][4k4..4k4+3] --------
__global__ __launch_bounds__(256) void luka_prep(const float* __restrict__ A,
                                                 f32x4* __restrict__ Apb) {
  int idx = blockIdx.x * 256 + threadIdx.x;   // 512 cols * 128 k4
  int o  = idx >> 7;
  int k4 = idx & 127;
  f32x4 v = *(const f32x4*)(A + o * NK + k4 * 4);      // coalesced read
  Apb[(((o >> 8) * 128) + k4) * 256 + (o & 255)] = v;  // 1MB one-shot
}

// ---- main -----------------------------------------------------------------
__global__ __launch_bounds__(1024, 4) void luka_main(
    const f32x4* __restrict__ Apb, const float* __restrict__ X,
    const float* __restrict__ Bv, float* __restrict__ Y) {
  __shared__ float lds[RPB * NK];        // 32KB X slab
  __shared__ float red[16 * 4 * CBL];    // 64KB merge buffer (4-row chunks)
  const int tid  = threadIdx.x;
  const int lane = tid & 63;
  const int w    = tid >> 6;             // wave id = K-sixteenth
  const int colblk  = blockIdx.x;        // 0..1
  const int rowBase = blockIdx.y * RPB;

  // Stage X[rowBase..+16)[0..512) -> lds row-major [16][512]; 2048 f32x4 by
  // 1024 threads in 2 rounds; per-wave LDS dest linear (base + lane*16) ✓.
  {
    const float* Xg = X + (size_t)rowBase * NK;
#pragma unroll
    for (int rnd = 0; rnd < 2; ++rnd) {
      int base = rnd * 1024 + w * 64;    // f32x4 index, wave-uniform
      async_load16(Xg + (size_t)(base + lane) * 4, &lds[base * 4]);
    }
  }

  // Wave's A stream: cols {lane,+64,+128,+192} of colblk panel, k-16th w.
  const f32x4* __restrict__ Aw =
      Apb + ((size_t)(colblk * 128 + w * KQ) * 256 + lane);

  float acc[RPB][4];
#pragma unroll
  for (int r = 0; r < RPB; ++r)
#pragma unroll
    for (int c = 0; c < 4; ++c) acc[r][c] = 0.0f;   // exact: ref clamps at 0

  // prime A double-buffer (j=0)
  f32x4 a[4], an[4];
#pragma unroll
  for (int c = 0; c < 4; ++c) a[c] = Aw[c * 64];

  __syncthreads();                       // staged X visible (vmcnt drain)

#pragma unroll
  for (int j = 0; j < KQ; ++j) {
    if (j + 1 < KQ) {
#pragma unroll
      for (int c = 0; c < 4; ++c) an[c] = Aw[(j + 1) * 256 + c * 64];
    }
    const int kb = (w * KQ + j) * 4;     // float col within x row
#pragma unroll
    for (int r = 0; r < RPB; ++r) {
      // LDS pipe: one broadcast ds_read_b128 amortized over 4 cols (1:16)
      const f32x4 xv = *(const f32x4*)&lds[r * NK + kb];
#pragma unroll
      for (int c = 0; c < 4; ++c) {
        f32x4 s = a[c] + xv;                          // 2x v_pk_add_f32
        acc[r][c] = fmaxf(fmaxf(s.x, s.y), acc[r][c]);  // v_max3
        acc[r][c] = fmaxf(fmaxf(s.z, s.w), acc[r][c]);  // v_max3
      }
    }
#pragma unroll
    for (int c = 0; c < 4; ++c) a[c] = an[c];
  }

  // 16-way K-merge: 4 passes x 4 rows through red[16][4][256].
  const int rc = tid >> 8;               // 0..3 : my reduce row
  const int cc = tid & 255;              // my reduce col (fixed across passes)
  const float bv = Bv[colblk * CBL + cc];
#pragma unroll 1
  for (int p = 0; p < 4; ++p) {
#pragma unroll
    for (int r2 = 0; r2 < 4; ++r2)
#pragma unroll
      for (int c = 0; c < 4; ++c)
        red[(w * 4 + r2) * CBL + c * 64 + lane] = acc[p * 4 + r2][c];
    __syncthreads();
    float m = red[rc * CBL + cc];
#pragma unroll
    for (int ww = 1; ww < 16; ++ww)
      m = fmaxf(m, red[(ww * 4 + rc) * CBL + cc]);
    float t = m - 1.0f;                  // defer of -1 is exact (monotone)
    Y[(size_t)(rowBase + p * 4 + rc) * NCOL + colblk * CBL + cc] =
        fmaxf(fmaxf(t, bv), 0.0f);       // v_max3
    __syncthreads();                     // red reused next pass
  }
}

// ---- fallback (R1 kernel, used only if d_ws < 1MB) ------------------------
#define TILE 64
#define BK   64
__global__ __launch_bounds__(256) void luka_fb(
    const float* __restrict__ X, const float* __restrict__ A,
    const float* __restrict__ Bv, float* __restrict__ Y) {
  __shared__ float xs[2][TILE * BK];
  __shared__ float as[2][TILE * BK];
  const int tid = threadIdx.x, wave = tid >> 6, tx = tid & 15, ty = tid >> 4;
  const int rowBase = blockIdx.y * TILE, colBase = blockIdx.x * TILE;
  uint32_t xoff[4], aoff[4];
#pragma unroll
  for (int r = 0; r < 4; ++r) {
    int row = ty * 4 + r;
    xoff[r] = (uint32_t)row * 256u + ((uint32_t)((row & 15) ^ (row >> 2)) << 4);
  }
#pragma unroll
  for (int c = 0; c < 4; ++c) {
    int row = tx * 4 + c;
    aoff[c] = (uint32_t)row * 256u + ((uint32_t)((row & 15) ^ (row >> 2)) << 4);
  }
  float acc[4][4];
#pragma unroll
  for (int r = 0; r < 4; ++r)
#pragma unroll
    for (int c = 0; c < 4; ++c) acc[r][c] = 0.0f;
  const int row0 = tid >> 4, sl = tid & 15;
  auto stage = [&](int buf, int kt) {
#pragma unroll
    for (int j = 0; j < 4; ++j) {
      int row = row0 + j * 16;
      int m = (row & 15) ^ (row >> 2);
      int kk = ((sl ^ m) << 2);
      async_load16(X + (size_t)(rowBase + row) * NK + kt * BK + kk,
                   &xs[buf][j * 1024 + wave * 256]);
      async_load16(A + (size_t)(colBase + row) * NK + kt * BK + kk,
                   &as[buf][j * 1024 + wave * 256]);
    }
  };
  stage(0, 0);
  __syncthreads();
  int buf = 0;
#pragma unroll 1
  for (int kt = 0; kt < NK / BK; ++kt) {
    if (kt < NK / BK - 1) stage(buf ^ 1, kt + 1);
    const char* xb = (const char*)&xs[buf][0];
    const char* ab = (const char*)&as[buf][0];
#pragma unroll
    for (int s4 = 0; s4 < BK / 4; ++s4) {
      f32x4 xf[4], af[4];
#pragma unroll
      for (int r = 0; r < 4; ++r)
        xf[r] = *(const f32x4*)(xb + (xoff[r] ^ (uint32_t)(s4 << 4)));
#pragma unroll
      for (int c = 0; c < 4; ++c)
        af[c] = *(const f32x4*)(ab + (aoff[c] ^ (uint32_t)(s4 << 4)));
#pragma unroll
      for (int r = 0; r < 4; ++r)
#pragma unroll
        for (int c = 0; c < 4; ++c) {
          f32x4 s = xf[r] + af[c];
          float t0 = fmaxf(fmaxf(s.x, s.y), acc[r][c]);
          acc[r][c] = fmaxf(fmaxf(s.z, s.w), t0);
        }
    }
    __syncthreads();
    buf ^= 1;
  }
  const f32x4 bv = *(const f32x4*)&Bv[colBase + tx * 4];
  float bvv[4] = {bv.x, bv.y, bv.z, bv.w};
#pragma unroll
  for (int r = 0; r < 4; ++r) {
    f32x4 o;
    o.x = fmaxf(fmaxf(acc[r][0] - 1.0f, bvv[0]), 0.0f);
    o.y = fmaxf(fmaxf(acc[r][1] - 1.0f, bvv[1]), 0.0f);
    o.z = fmaxf(fmaxf(acc[r][2] - 1.0f, bvv[2]), 0.0f);
    o.w = fmaxf(fmaxf(acc[r][3] - 1.0f, bvv[3]), 0.0f);
    *(f32x4*)&Y[(size_t)(rowBase + ty * 4 + r) * NCOL + colBase + tx * 4] = o;
  }
}

extern "C" void kernel_launch(void* const* d_in, const int* in_sizes, int n_in,
                              void* d_out, int out_size, void* d_ws, size_t ws_size,
                              hipStream_t stream) {
  const float* X = (const float*)d_in[0];   // [2048][512]
  const float* A = (const float*)d_in[1];   // [512][512]
  const float* B = (const float*)d_in[2];   // [512]
  float* Y = (float*)d_out;                 // [2048][512]

  if (ws_size >= (size_t)NCOL * NK * sizeof(float)) {
    f32x4* Apb = (f32x4*)d_ws;
    luka_prep<<<dim3(NCOL * NK / 4 / 256), dim3(256), 0, stream>>>(A, Apb);
    dim3 grid(NCOL / CBL, NROW / RPB);      // (2, 128) = 256 blocks, 1/CU
    luka_main<<<grid, dim3(1024), 0, stream>>>(Apb, X, B, Y);
  } else {
    dim3 grid(NCOL / TILE, NROW / TILE);    // fallback: R1 kernel
    luka_fb<<<grid, dim3(256), 0, stream>>>(X, A, B, Y);
  }
}

// Round 9
// 85.583 us; speedup vs baseline: 1.7056x; 1.7056x over previous
//
#include <hip/hip_runtime.h>
#include <cstdint>

// Lukasiewicz max-plus matmul: y[n,o] = max(b[o], max(0, max_i(x[n,i]+a[o,i]-1)))
// N=2048, K=512, OUT=512, fp32.
//
// R9 = R8 structure + rule-#20 fix. R8's merge loop was `unroll 1`, so
// acc[p*4+r2][c] was runtime-indexed -> compiler demoted the WHOLE acc array
// to scratch (WRITE_SIZE 350MB, VGPR=60, VALUBusy 15%). Fix: fully unroll the
// merge so all acc indices are static; drop explicit A dbuf (j-loop is fully
// unrolled; scheduler hoists loads) to stay under the 128-VGPR cap.
//
// Structure: block = 1024 thr (16 waves) x 16 rows x 256 cols (4 cols/lane,
// ds:VALU = 1:16), 16-way k-split (duplicate-free), grid (2,128) = 256 blocks
// = exactly 1/CU, X slab 32KB LDS broadcast, merge via 64KB red (96KB total).

#define NROW 2048
#define NK   512
#define NCOL 512
#define RPB  16                   // rows per block
#define CBL  256                  // cols per block (4 per lane)
#define KQ   8                    // k4-steps per wave (128 / 16 waves)
typedef float f32x4 __attribute__((ext_vector_type(4)));

__device__ __forceinline__ void async_load16(const float* g, float* l) {
  __builtin_amdgcn_global_load_lds(
      (const __attribute__((address_space(1))) void*)g,
      (__attribute__((address_space(3))) void*)l, 16, 0, 0);
}

// ---- prep: Apb[((o>>8)*128 + k4)*256 + (o&255)] = A[o][4k4..4k4+3] --------
__global__ __launch_bounds__(256) void luka_prep(const float* __restrict__ A,
                                                 f32x4* __restrict__ Apb) {
  int idx = blockIdx.x * 256 + threadIdx.x;   // 512 cols * 128 k4
  int o  = idx >> 7;
  int k4 = idx & 127;
  f32x4 v = *(const f32x4*)(A + o * NK + k4 * 4);      // coalesced read
  Apb[(((o >> 8) * 128) + k4) * 256 + (o & 255)] = v;  // 1MB one-shot
}

// ---- main -----------------------------------------------------------------
__global__ __launch_bounds__(1024, 4) void luka_main(
    const f32x4* __restrict__ Apb, const float* __restrict__ X,
    const float* __restrict__ Bv, float* __restrict__ Y) {
  __shared__ float lds[RPB * NK];        // 32KB X slab
  __shared__ float red[16 * 4 * CBL];    // 64KB merge buffer (4-row chunks)
  const int tid  = threadIdx.x;
  const int lane = tid & 63;
  const int w    = tid >> 6;             // wave id = K-sixteenth
  const int colblk  = blockIdx.x;        // 0..1
  const int rowBase = blockIdx.y * RPB;

  // Stage X[rowBase..+16)[0..512) -> lds row-major [16][512]; 2048 f32x4 by
  // 1024 threads in 2 rounds; per-wave LDS dest linear (base + lane*16) ✓.
  {
    const float* Xg = X + (size_t)rowBase * NK;
#pragma unroll
    for (int rnd = 0; rnd < 2; ++rnd) {
      int base = rnd * 1024 + w * 64;    // f32x4 index, wave-uniform
      async_load16(Xg + (size_t)(base + lane) * 4, &lds[base * 4]);
    }
  }

  // Wave's A stream: cols {lane,+64,+128,+192} of colblk panel, k-16th w.
  const f32x4* __restrict__ Aw =
      Apb + ((size_t)(colblk * 128 + w * KQ) * 256 + lane);

  float acc[RPB][4];
#pragma unroll
  for (int r = 0; r < RPB; ++r)
#pragma unroll
    for (int c = 0; c < 4; ++c) acc[r][c] = 0.0f;   // exact: ref clamps at 0

  __syncthreads();                       // staged X visible (vmcnt drain)

#pragma unroll
  for (int j = 0; j < KQ; ++j) {         // fully unrolled: static everything
    f32x4 a0 = Aw[j * 256];
    f32x4 a1 = Aw[j * 256 + 64];
    f32x4 a2 = Aw[j * 256 + 128];
    f32x4 a3 = Aw[j * 256 + 192];
    const int kb = (w * KQ + j) * 4;     // float col within x row
#pragma unroll
    for (int r = 0; r < RPB; ++r) {
      // LDS pipe: one broadcast ds_read_b128 amortized over 4 cols (1:16)
      const f32x4 xv = *(const f32x4*)&lds[r * NK + kb];
      f32x4 s0 = a0 + xv;                             // v_pk_add_f32 x2 each
      f32x4 s1 = a1 + xv;
      f32x4 s2 = a2 + xv;
      f32x4 s3 = a3 + xv;
      acc[r][0] = fmaxf(fmaxf(s0.x, s0.y), acc[r][0]);  // v_max3
      acc[r][0] = fmaxf(fmaxf(s0.z, s0.w), acc[r][0]);
      acc[r][1] = fmaxf(fmaxf(s1.x, s1.y), acc[r][1]);
      acc[r][1] = fmaxf(fmaxf(s1.z, s1.w), acc[r][1]);
      acc[r][2] = fmaxf(fmaxf(s2.x, s2.y), acc[r][2]);
      acc[r][2] = fmaxf(fmaxf(s2.z, s2.w), acc[r][2]);
      acc[r][3] = fmaxf(fmaxf(s3.x, s3.y), acc[r][3]);
      acc[r][3] = fmaxf(fmaxf(s3.z, s3.w), acc[r][3]);
    }
  }

  // 16-way K-merge: 4 passes x 4 rows through red[16][4][256].
  // FULLY UNROLLED (rule #20): acc indices must be compile-time constants.
  const int rc = tid >> 8;               // 0..3 : my reduce row
  const int cc = tid & 255;              // my reduce col
  const float bv = Bv[colblk * CBL + cc];
#pragma unroll
  for (int p = 0; p < 4; ++p) {          // static p -> acc stays in VGPRs
#pragma unroll
    for (int r2 = 0; r2 < 4; ++r2)
#pragma unroll
      for (int c = 0; c < 4; ++c)
        red[(w * 4 + r2) * CBL + c * 64 + lane] = acc[p * 4 + r2][c];
    __syncthreads();
    float m = red[rc * CBL + cc];
#pragma unroll
    for (int ww = 1; ww < 16; ++ww)
      m = fmaxf(m, red[(ww * 4 + rc) * CBL + cc]);
    float t = m - 1.0f;                  // defer of -1 is exact (monotone)
    Y[(size_t)(rowBase + p * 4 + rc) * NCOL + colblk * CBL + cc] =
        fmaxf(fmaxf(t, bv), 0.0f);       // v_max3
    __syncthreads();                     // red reused next pass
  }
}

// ---- fallback (R1 kernel, used only if d_ws < 1MB) ------------------------
#define TILE 64
#define BK   64
__global__ __launch_bounds__(256) void luka_fb(
    const float* __restrict__ X, const float* __restrict__ A,
    const float* __restrict__ Bv, float* __restrict__ Y) {
  __shared__ float xs[2][TILE * BK];
  __shared__ float as[2][TILE * BK];
  const int tid = threadIdx.x, wave = tid >> 6, tx = tid & 15, ty = tid >> 4;
  const int rowBase = blockIdx.y * TILE, colBase = blockIdx.x * TILE;
  uint32_t xoff[4], aoff[4];
#pragma unroll
  for (int r = 0; r < 4; ++r) {
    int row = ty * 4 + r;
    xoff[r] = (uint32_t)row * 256u + ((uint32_t)((row & 15) ^ (row >> 2)) << 4);
  }
#pragma unroll
  for (int c = 0; c < 4; ++c) {
    int row = tx * 4 + c;
    aoff[c] = (uint32_t)row * 256u + ((uint32_t)((row & 15) ^ (row >> 2)) << 4);
  }
  float acc[4][4];
#pragma unroll
  for (int r = 0; r < 4; ++r)
#pragma unroll
    for (int c = 0; c < 4; ++c) acc[r][c] = 0.0f;
  const int row0 = tid >> 4, sl = tid & 15;
  auto stage = [&](int buf, int kt) {
#pragma unroll
    for (int j = 0; j < 4; ++j) {
      int row = row0 + j * 16;
      int m = (row & 15) ^ (row >> 2);
      int kk = ((sl ^ m) << 2);
      async_load16(X + (size_t)(rowBase + row) * NK + kt * BK + kk,
                   &xs[buf][j * 1024 + wave * 256]);
      async_load16(A + (size_t)(colBase + row) * NK + kt * BK + kk,
                   &as[buf][j * 1024 + wave * 256]);
    }
  };
  stage(0, 0);
  __syncthreads();
  int buf = 0;
#pragma unroll 1
  for (int kt = 0; kt < NK / BK; ++kt) {
    if (kt < NK / BK - 1) stage(buf ^ 1, kt + 1);
    const char* xb = (const char*)&xs[buf][0];
    const char* ab = (const char*)&as[buf][0];
#pragma unroll
    for (int s4 = 0; s4 < BK / 4; ++s4) {
      f32x4 xf[4], af[4];
#pragma unroll
      for (int r = 0; r < 4; ++r)
        xf[r] = *(const f32x4*)(xb + (xoff[r] ^ (uint32_t)(s4 << 4)));
#pragma unroll
      for (int c = 0; c < 4; ++c)
        af[c] = *(const f32x4*)(ab + (aoff[c] ^ (uint32_t)(s4 << 4)));
#pragma unroll
      for (int r = 0; r < 4; ++r)
#pragma unroll
        for (int c = 0; c < 4; ++c) {
          f32x4 s = xf[r] + af[c];
          float t0 = fmaxf(fmaxf(s.x, s.y), acc[r][c]);
          acc[r][c] = fmaxf(fmaxf(s.z, s.w), t0);
        }
    }
    __syncthreads();
    buf ^= 1;
  }
  const f32x4 bv = *(const f32x4*)&Bv[colBase + tx * 4];
  float bvv[4] = {bv.x, bv.y, bv.z, bv.w};
#pragma unroll
  for (int r = 0; r < 4; ++r) {
    f32x4 o;
    o.x = fmaxf(fmaxf(acc[r][0] - 1.0f, bvv[0]), 0.0f);
    o.y = fmaxf(fmaxf(acc[r][1] - 1.0f, bvv[1]), 0.0f);
    o.z = fmaxf(fmaxf(acc[r][2] - 1.0f, bvv[2]), 0.0f);
    o.w = fmaxf(fmaxf(acc[r][3] - 1.0f, bvv[3]), 0.0f);
    *(f32x4*)&Y[(size_t)(rowBase + ty * 4 + r) * NCOL + colBase + tx * 4] = o;
  }
}

extern "C" void kernel_launch(void* const* d_in, const int* in_sizes, int n_in,
                              void* d_out, int out_size, void* d_ws, size_t ws_size,
                              hipStream_t stream) {
  const float* X = (const float*)d_in[0];   // [2048][512]
  const float* A = (const float*)d_in[1];   // [512][512]
  const float* B = (const float*)d_in[2];   // [512]
  float* Y = (float*)d_out;                 // [2048][512]

  if (ws_size >= (size_t)NCOL * NK * sizeof(float)) {
    f32x4* Apb = (f32x4*)d_ws;
    luka_prep<<<dim3(NCOL * NK / 4 / 256), dim3(256), 0, stream>>>(A, Apb);
    dim3 grid(NCOL / CBL, NROW / RPB);      // (2, 128) = 256 blocks, 1/CU
    luka_main<<<grid, dim3(1024), 0, stream>>>(Apb, X, B, Y);
  } else {
    dim3 grid(NCOL / TILE, NROW / TILE);    // fallback: R1 kernel
    luka_fb<<<grid, dim3(256), 0, stream>>>(X, A, B, Y);
  }
}